// Round 1
// baseline (785.717 us; speedup 1.0000x reference)
//
#include <hip/hip_runtime.h>
#include <stdint.h>

// MoE MLP: per expert e (8): gate_up = h_e(1024x2048) @ W1_e(2048x4096),
// act = up * relu(gate) (bf16, ws), out_e = act @ W2_e(2048x2048) -> fp32.
// bf16 MFMA (16x16x32), fp32->bf16 round-half-up at staging time.

#define NEXP 8
#define DIM  2048
#define TOK  1024
#define NGU  4096
#define BM   128
#define BN   128
#define BK   32
#define LDST 40   // BK + 8 pad (ushorts): 80B row stride -> 2-way LDS aliasing (free)

typedef __attribute__((ext_vector_type(8))) short short8;
typedef __attribute__((ext_vector_type(4))) float f32x4;

// pack two fp32 -> two bf16 (round-half-up): 2 adds + 1 v_perm
__device__ __forceinline__ uint32_t pkbf(float lo, float hi) {
  return __builtin_amdgcn_perm(__float_as_uint(hi) + 0x8000u,
                               __float_as_uint(lo) + 0x8000u, 0x07060302u);
}

__device__ __forceinline__ uint16_t bf16_rne(float x) {
  uint32_t u = __float_as_uint(x);
  return (uint16_t)((u + 0x7fffu + ((u >> 16) & 1u)) >> 16);
}

// K1: act[e] = up * relu(gate), fused dual-accumulator GEMM.
__global__ __launch_bounds__(256, 2) void k_gateup(const float* __restrict__ H,
                                                   const float* __restrict__ W1,
                                                   uint16_t* __restrict__ ACT) {
  __shared__ uint16_t As[BM * LDST];
  __shared__ uint16_t Bg[BN * LDST];
  __shared__ uint16_t Bu[BN * LDST];

  const int tid = threadIdx.x;
  const int e   = blockIdx.z;
  const int m0  = blockIdx.y * BM;
  const int n0  = blockIdx.x * BN;

  const float* hA = H + (size_t)(e * TOK + m0) * DIM;
  const float* wE = W1 + (size_t)e * DIM * NGU;

  // A staging: thread -> (row, 16-wide k half)
  const int ar = tid >> 1;
  const int ak = (tid & 1) << 4;
  const float* aptr = hA + (size_t)ar * DIM + ak;
  uint16_t* asw = &As[ar * LDST + ak];

  // B staging (transposed into LDS): thread -> (col n, 16-wide k half)
  const int bn = tid & 127;
  const int bk = (tid >> 7) << 4;
  const float* gptr = wE + (size_t)bk * NGU + (n0 + bn);
  const float* uptr = gptr + DIM;   // up columns at +2048
  uint16_t* bgw = &Bg[bn * LDST + bk];
  uint16_t* buw = &Bu[bn * LDST + bk];

  const int lane = tid & 63;
  const int wid  = tid >> 6;
  const int wr = (wid >> 1) << 6;   // wave row base (2x2 waves over 128x128)
  const int wc = (wid & 1) << 6;    // wave col base
  const int lm = lane & 15;
  const int qd = lane >> 4;

  f32x4 accg[4][4], accu[4][4];
  const f32x4 zero = {0.f, 0.f, 0.f, 0.f};
#pragma unroll
  for (int i = 0; i < 4; ++i)
#pragma unroll
    for (int j = 0; j < 4; ++j) { accg[i][j] = zero; accu[i][j] = zero; }

  const uint16_t* afr = &As[(wr + lm) * LDST + (qd << 3)];
  const uint16_t* gfr = &Bg[(wc + lm) * LDST + (qd << 3)];
  const uint16_t* ufr = &Bu[(wc + lm) * LDST + (qd << 3)];

  for (int k0 = 0; k0 < DIM; k0 += BK) {
    // global loads + convert to packed bf16 in regs (before barrier)
    float4 a0 = *(const float4*)(aptr + 0);
    float4 a1 = *(const float4*)(aptr + 4);
    float4 a2 = *(const float4*)(aptr + 8);
    float4 a3 = *(const float4*)(aptr + 12);
    uint4 aw0 = make_uint4(pkbf(a0.x, a0.y), pkbf(a0.z, a0.w),
                           pkbf(a1.x, a1.y), pkbf(a1.z, a1.w));
    uint4 aw1 = make_uint4(pkbf(a2.x, a2.y), pkbf(a2.z, a2.w),
                           pkbf(a3.x, a3.y), pkbf(a3.z, a3.w));

    float g[16], u[16];
#pragma unroll
    for (int i = 0; i < 16; ++i) g[i] = gptr[(size_t)i * NGU];
#pragma unroll
    for (int i = 0; i < 16; ++i) u[i] = uptr[(size_t)i * NGU];
    uint4 gw0 = make_uint4(pkbf(g[0], g[1]),  pkbf(g[2], g[3]),
                           pkbf(g[4], g[5]),  pkbf(g[6], g[7]));
    uint4 gw1 = make_uint4(pkbf(g[8], g[9]),  pkbf(g[10], g[11]),
                           pkbf(g[12], g[13]), pkbf(g[14], g[15]));
    uint4 uw0 = make_uint4(pkbf(u[0], u[1]),  pkbf(u[2], u[3]),
                           pkbf(u[4], u[5]),  pkbf(u[6], u[7]));
    uint4 uw1 = make_uint4(pkbf(u[8], u[9]),  pkbf(u[10], u[11]),
                           pkbf(u[12], u[13]), pkbf(u[14], u[15]));

    __syncthreads();              // prev tile fully consumed
    *(uint4*)(asw)     = aw0;
    *(uint4*)(asw + 8) = aw1;
    *(uint4*)(bgw)     = gw0;
    *(uint4*)(bgw + 8) = gw1;
    *(uint4*)(buw)     = uw0;
    *(uint4*)(buw + 8) = uw1;
    __syncthreads();

    short8 a[4], bgf[4], buf[4];
#pragma unroll
    for (int i = 0; i < 4; ++i) a[i] = *(const short8*)(afr + i * 16 * LDST);
#pragma unroll
    for (int j = 0; j < 4; ++j) {
      bgf[j] = *(const short8*)(gfr + j * 16 * LDST);
      buf[j] = *(const short8*)(ufr + j * 16 * LDST);
    }
#pragma unroll
    for (int i = 0; i < 4; ++i)
#pragma unroll
      for (int j = 0; j < 4; ++j) {
        accg[i][j] = __builtin_amdgcn_mfma_f32_16x16x32_bf16(a[i], bgf[j], accg[i][j], 0, 0, 0);
        accu[i][j] = __builtin_amdgcn_mfma_f32_16x16x32_bf16(a[i], buf[j], accu[i][j], 0, 0, 0);
      }

    aptr += BK;
    gptr += (size_t)BK * NGU;
    uptr += (size_t)BK * NGU;
  }

  // epilogue: act = up * relu(gate) -> bf16 (RNE)
  uint16_t* actE = ACT + (size_t)(e * TOK + m0) * DIM + n0;
#pragma unroll
  for (int i = 0; i < 4; ++i)
#pragma unroll
    for (int j = 0; j < 4; ++j)
#pragma unroll
      for (int t = 0; t < 4; ++t) {
        int row = wr + i * 16 + qd * 4 + t;   // C/D layout: row=quad*4+reg
        int col = wc + j * 16 + lm;           //            col=lane&15
        float gv = accg[i][j][t];
        float uv = accu[i][j][t];
        actE[(size_t)row * DIM + col] = bf16_rne(uv * fmaxf(gv, 0.f));
      }
}

// K2: out[e] = act[e] @ W2[e]
__global__ __launch_bounds__(256, 3) void k_down(const uint16_t* __restrict__ ACT,
                                                 const float* __restrict__ W2,
                                                 float* __restrict__ OUT) {
  __shared__ uint16_t As[BM * LDST];
  __shared__ uint16_t Bs[BN * LDST];

  const int tid = threadIdx.x;
  const int e   = blockIdx.z;
  const int m0  = blockIdx.y * BM;
  const int n0  = blockIdx.x * BN;

  const uint16_t* aA = ACT + (size_t)(e * TOK + m0) * DIM;
  const float* wE = W2 + (size_t)e * DIM * DIM;

  const int ar = tid >> 1;
  const int ak = (tid & 1) << 4;
  const uint16_t* aptr = aA + (size_t)ar * DIM + ak;
  uint16_t* asw = &As[ar * LDST + ak];

  const int bn = tid & 127;
  const int bk = (tid >> 7) << 4;
  const float* bptr = wE + (size_t)bk * DIM + (n0 + bn);
  uint16_t* bsw = &Bs[bn * LDST + bk];

  const int lane = tid & 63;
  const int wid  = tid >> 6;
  const int wr = (wid >> 1) << 6;
  const int wc = (wid & 1) << 6;
  const int lm = lane & 15;
  const int qd = lane >> 4;

  f32x4 acc[4][4];
  const f32x4 zero = {0.f, 0.f, 0.f, 0.f};
#pragma unroll
  for (int i = 0; i < 4; ++i)
#pragma unroll
    for (int j = 0; j < 4; ++j) acc[i][j] = zero;

  const uint16_t* afr = &As[(wr + lm) * LDST + (qd << 3)];
  const uint16_t* bfr = &Bs[(wc + lm) * LDST + (qd << 3)];

  for (int k0 = 0; k0 < DIM; k0 += BK) {
    // A is already bf16: straight 16B copies
    uint4 aw0 = *(const uint4*)(aptr);
    uint4 aw1 = *(const uint4*)(aptr + 8);
    float b[16];
#pragma unroll
    for (int i = 0; i < 16; ++i) b[i] = bptr[(size_t)i * DIM];
    uint4 bw0 = make_uint4(pkbf(b[0], b[1]),  pkbf(b[2], b[3]),
                           pkbf(b[4], b[5]),  pkbf(b[6], b[7]));
    uint4 bw1 = make_uint4(pkbf(b[8], b[9]),  pkbf(b[10], b[11]),
                           pkbf(b[12], b[13]), pkbf(b[14], b[15]));

    __syncthreads();
    *(uint4*)(asw)     = aw0;
    *(uint4*)(asw + 8) = aw1;
    *(uint4*)(bsw)     = bw0;
    *(uint4*)(bsw + 8) = bw1;
    __syncthreads();

    short8 a[4], bf[4];
#pragma unroll
    for (int i = 0; i < 4; ++i) a[i] = *(const short8*)(afr + i * 16 * LDST);
#pragma unroll
    for (int j = 0; j < 4; ++j) bf[j] = *(const short8*)(bfr + j * 16 * LDST);
#pragma unroll
    for (int i = 0; i < 4; ++i)
#pragma unroll
      for (int j = 0; j < 4; ++j)
        acc[i][j] = __builtin_amdgcn_mfma_f32_16x16x32_bf16(a[i], bf[j], acc[i][j], 0, 0, 0);

    aptr += BK;
    bptr += (size_t)BK * DIM;
  }

  float* outE = OUT + (size_t)(e * TOK + m0) * DIM + n0;
#pragma unroll
  for (int i = 0; i < 4; ++i)
#pragma unroll
    for (int j = 0; j < 4; ++j)
#pragma unroll
      for (int t = 0; t < 4; ++t) {
        int row = wr + i * 16 + qd * 4 + t;
        int col = wc + j * 16 + lm;
        outE[(size_t)row * DIM + col] = acc[i][j][t];
      }
}

extern "C" void kernel_launch(void* const* d_in, const int* in_sizes, int n_in,
                              void* d_out, int out_size, void* d_ws, size_t ws_size,
                              hipStream_t stream) {
  const float* H  = (const float*)d_in[0];   // (8192, 2048) fp32
  const float* W1 = (const float*)d_in[1];   // (8, 2048, 4096) fp32
  const float* W2 = (const float*)d_in[2];   // (8, 2048, 2048) fp32
  float* OUT = (float*)d_out;                // (8192, 2048) fp32
  uint16_t* ACT = (uint16_t*)d_ws;           // 8*1024*2048 bf16 = 33.5 MB

  dim3 blk(256);
  dim3 g1(DIM / BN, TOK / BM, NEXP);         // 16 x 8 x 8
  k_gateup<<<g1, blk, 0, stream>>>(H, W1, ACT);
  dim3 g2(DIM / BN, TOK / BM, NEXP);
  k_down<<<g2, blk, 0, stream>>>(ACT, W2, OUT);
}

// Round 2
// 777.830 us; speedup vs baseline: 1.0101x; 1.0101x over previous
//
#include <hip/hip_runtime.h>
#include <stdint.h>

// MoE MLP: per expert e (8): gate_up = h_e(1024x2048) @ W1_e(2048x4096),
// act = up * relu(gate) (bf16, ws), out_e = act @ W2_e(2048x2048) -> fp32.
// bf16 MFMA (16x16x32). R1: software prefetch (loads for tile k+1 issued
// before MFMA of tile k); K2 loads A-fragments direct from global (bf16).

#define NEXP 8
#define DIM  2048
#define TOK  1024
#define NGU  4096
#define BM   128
#define BN   128
#define BK   32
#define LDST 40   // BK + 8 pad (ushorts): 80B row stride -> 2-way LDS aliasing (free)

typedef __attribute__((ext_vector_type(8))) short short8;
typedef __attribute__((ext_vector_type(4))) float f32x4;

// pack two fp32 -> two bf16 (round-half-up): 2 adds + 1 v_perm
__device__ __forceinline__ uint32_t pkbf(float lo, float hi) {
  return __builtin_amdgcn_perm(__float_as_uint(hi) + 0x8000u,
                               __float_as_uint(lo) + 0x8000u, 0x07060302u);
}

__device__ __forceinline__ uint16_t bf16_rne(float x) {
  uint32_t u = __float_as_uint(x);
  return (uint16_t)((u + 0x7fffu + ((u >> 16) & 1u)) >> 16);
}

// K1: act[e] = up * relu(gate), fused dual-accumulator GEMM, prefetched.
__global__ __launch_bounds__(256, 2) void k_gateup(const float* __restrict__ H,
                                                   const float* __restrict__ W1,
                                                   uint16_t* __restrict__ ACT) {
  __shared__ uint16_t As[BM * LDST];
  __shared__ uint16_t Bg[BN * LDST];
  __shared__ uint16_t Bu[BN * LDST];

  const int tid = threadIdx.x;
  const int e   = blockIdx.z;
  const int m0  = blockIdx.y * BM;
  const int n0  = blockIdx.x * BN;

  const float* hA = H + (size_t)(e * TOK + m0) * DIM;
  const float* wE = W1 + (size_t)e * DIM * NGU;

  // A staging: thread -> (row, 16-wide k half)
  const int ar = tid >> 1;
  const int ak = (tid & 1) << 4;
  const float* aptr = hA + (size_t)ar * DIM + ak;
  uint16_t* asw = &As[ar * LDST + ak];

  // B staging (transposed into LDS): thread -> (col n, 16-wide k half)
  const int bn = tid & 127;
  const int bk = (tid >> 7) << 4;
  const float* gptr = wE + (size_t)bk * NGU + (n0 + bn);
  const float* uptr = gptr + DIM;
  uint16_t* bgw = &Bg[bn * LDST + bk];
  uint16_t* buw = &Bu[bn * LDST + bk];

  const int lane = tid & 63;
  const int wid  = tid >> 6;
  const int wr = (wid >> 1) << 6;
  const int wc = (wid & 1) << 6;
  const int lm = lane & 15;
  const int qd = lane >> 4;

  f32x4 accg[4][4], accu[4][4];
  const f32x4 zero = {0.f, 0.f, 0.f, 0.f};
#pragma unroll
  for (int i = 0; i < 4; ++i)
#pragma unroll
    for (int j = 0; j < 4; ++j) { accg[i][j] = zero; accu[i][j] = zero; }

  const uint16_t* afr = &As[(wr + lm) * LDST + (qd << 3)];
  const uint16_t* gfr = &Bg[(wc + lm) * LDST + (qd << 3)];
  const uint16_t* ufr = &Bu[(wc + lm) * LDST + (qd << 3)];

  // ---- prologue: prefetch tile 0 into registers ----
  float4 a0 = *(const float4*)(aptr + 0);
  float4 a1 = *(const float4*)(aptr + 4);
  float4 a2 = *(const float4*)(aptr + 8);
  float4 a3 = *(const float4*)(aptr + 12);
  float g[16], u[16];
#pragma unroll
  for (int i = 0; i < 16; ++i) g[i] = gptr[(size_t)i * NGU];
#pragma unroll
  for (int i = 0; i < 16; ++i) u[i] = uptr[(size_t)i * NGU];

#pragma unroll 1
  for (int k0 = 0; k0 < DIM; k0 += BK) {
    // pack current tile (s_waitcnt vmcnt lands here — covered by prev MFMAs)
    uint4 aw0 = make_uint4(pkbf(a0.x, a0.y), pkbf(a0.z, a0.w),
                           pkbf(a1.x, a1.y), pkbf(a1.z, a1.w));
    uint4 aw1 = make_uint4(pkbf(a2.x, a2.y), pkbf(a2.z, a2.w),
                           pkbf(a3.x, a3.y), pkbf(a3.z, a3.w));
    uint4 gw0 = make_uint4(pkbf(g[0], g[1]),  pkbf(g[2], g[3]),
                           pkbf(g[4], g[5]),  pkbf(g[6], g[7]));
    uint4 gw1 = make_uint4(pkbf(g[8], g[9]),  pkbf(g[10], g[11]),
                           pkbf(g[12], g[13]), pkbf(g[14], g[15]));
    uint4 uw0 = make_uint4(pkbf(u[0], u[1]),  pkbf(u[2], u[3]),
                           pkbf(u[4], u[5]),  pkbf(u[6], u[7]));
    uint4 uw1 = make_uint4(pkbf(u[8], u[9]),  pkbf(u[10], u[11]),
                           pkbf(u[12], u[13]), pkbf(u[14], u[15]));

    __syncthreads();
    *(uint4*)(asw)     = aw0;
    *(uint4*)(asw + 8) = aw1;
    *(uint4*)(bgw)     = gw0;
    *(uint4*)(bgw + 8) = gw1;
    *(uint4*)(buw)     = uw0;
    *(uint4*)(buw + 8) = uw1;
    __syncthreads();

    // issue next tile's global loads NOW — overlapped with ds_read + MFMA below
    aptr += BK;
    gptr += (size_t)BK * NGU;
    uptr += (size_t)BK * NGU;
    if (k0 + BK < DIM) {
      a0 = *(const float4*)(aptr + 0);
      a1 = *(const float4*)(aptr + 4);
      a2 = *(const float4*)(aptr + 8);
      a3 = *(const float4*)(aptr + 12);
#pragma unroll
      for (int i = 0; i < 16; ++i) g[i] = gptr[(size_t)i * NGU];
#pragma unroll
      for (int i = 0; i < 16; ++i) u[i] = uptr[(size_t)i * NGU];
    }

    short8 a[4], bgf[4], buf[4];
#pragma unroll
    for (int i = 0; i < 4; ++i) a[i] = *(const short8*)(afr + i * 16 * LDST);
#pragma unroll
    for (int j = 0; j < 4; ++j) {
      bgf[j] = *(const short8*)(gfr + j * 16 * LDST);
      buf[j] = *(const short8*)(ufr + j * 16 * LDST);
    }
#pragma unroll
    for (int i = 0; i < 4; ++i)
#pragma unroll
      for (int j = 0; j < 4; ++j) {
        accg[i][j] = __builtin_amdgcn_mfma_f32_16x16x32_bf16(a[i], bgf[j], accg[i][j], 0, 0, 0);
        accu[i][j] = __builtin_amdgcn_mfma_f32_16x16x32_bf16(a[i], buf[j], accu[i][j], 0, 0, 0);
      }
  }

  // epilogue: act = up * relu(gate) -> bf16 (RNE)
  uint16_t* actE = ACT + (size_t)(e * TOK + m0) * DIM + n0;
#pragma unroll
  for (int i = 0; i < 4; ++i)
#pragma unroll
    for (int j = 0; j < 4; ++j)
#pragma unroll
      for (int t = 0; t < 4; ++t) {
        int row = wr + i * 16 + qd * 4 + t;
        int col = wc + j * 16 + lm;
        float gv = accg[i][j][t];
        float uv = accu[i][j][t];
        actE[(size_t)row * DIM + col] = bf16_rne(uv * fmaxf(gv, 0.f));
      }
}

// K2: out[e] = act[e] @ W2[e]. A (bf16) fragments loaded DIRECT from global
// (k-contiguous 16B per lane), prefetched; B staged via LDS, prefetched.
__global__ __launch_bounds__(256, 2) void k_down(const uint16_t* __restrict__ ACT,
                                                 const float* __restrict__ W2,
                                                 float* __restrict__ OUT) {
  __shared__ uint16_t Bs[BN * LDST];

  const int tid = threadIdx.x;
  const int e   = blockIdx.z;
  const int m0  = blockIdx.y * BM;
  const int n0  = blockIdx.x * BN;

  const uint16_t* aA = ACT + (size_t)(e * TOK + m0) * DIM;
  const float* wE = W2 + (size_t)e * DIM * DIM;

  const int bn = tid & 127;
  const int bk = (tid >> 7) << 4;
  const float* bptr = wE + (size_t)bk * DIM + (n0 + bn);
  uint16_t* bsw = &Bs[bn * LDST + bk];

  const int lane = tid & 63;
  const int wid  = tid >> 6;
  const int wr = (wid >> 1) << 6;
  const int wc = (wid & 1) << 6;
  const int lm = lane & 15;
  const int qd = lane >> 4;

  // A-fragment global base: row = wr + i*16 + lm, k = k0 + qd*8 (8 bf16 = 16B)
  const uint16_t* agp = aA + (size_t)(wr + lm) * DIM + (qd << 3);

  f32x4 acc[4][4];
  const f32x4 zero = {0.f, 0.f, 0.f, 0.f};
#pragma unroll
  for (int i = 0; i < 4; ++i)
#pragma unroll
    for (int j = 0; j < 4; ++j) acc[i][j] = zero;

  const uint16_t* bfr = &Bs[(wc + lm) * LDST + (qd << 3)];

  // ---- prologue: prefetch tile 0 ----
  short8 an[4];
#pragma unroll
  for (int i = 0; i < 4; ++i) an[i] = *(const short8*)(agp + (size_t)i * 16 * DIM);
  float b[16];
#pragma unroll
  for (int i = 0; i < 16; ++i) b[i] = bptr[(size_t)i * DIM];

#pragma unroll 1
  for (int k0 = 0; k0 < DIM; k0 += BK) {
    uint4 bw0 = make_uint4(pkbf(b[0], b[1]),  pkbf(b[2], b[3]),
                           pkbf(b[4], b[5]),  pkbf(b[6], b[7]));
    uint4 bw1 = make_uint4(pkbf(b[8], b[9]),  pkbf(b[10], b[11]),
                           pkbf(b[12], b[13]), pkbf(b[14], b[15]));
    short8 a[4];
#pragma unroll
    for (int i = 0; i < 4; ++i) a[i] = an[i];   // current A frags

    __syncthreads();
    *(uint4*)(bsw)     = bw0;
    *(uint4*)(bsw + 8) = bw1;
    __syncthreads();

    // prefetch next tile
    bptr += (size_t)BK * DIM;
    agp  += BK;
    if (k0 + BK < DIM) {
#pragma unroll
      for (int i = 0; i < 4; ++i) an[i] = *(const short8*)(agp + (size_t)i * 16 * DIM);
#pragma unroll
      for (int i = 0; i < 16; ++i) b[i] = bptr[(size_t)i * DIM];
    }

    short8 bf[4];
#pragma unroll
    for (int j = 0; j < 4; ++j) bf[j] = *(const short8*)(bfr + j * 16 * LDST);
#pragma unroll
    for (int i = 0; i < 4; ++i)
#pragma unroll
      for (int j = 0; j < 4; ++j)
        acc[i][j] = __builtin_amdgcn_mfma_f32_16x16x32_bf16(a[i], bf[j], acc[i][j], 0, 0, 0);
  }

  float* outE = OUT + (size_t)(e * TOK + m0) * DIM + n0;
#pragma unroll
  for (int i = 0; i < 4; ++i)
#pragma unroll
    for (int j = 0; j < 4; ++j)
#pragma unroll
      for (int t = 0; t < 4; ++t) {
        int row = wr + i * 16 + qd * 4 + t;
        int col = wc + j * 16 + lm;
        outE[(size_t)row * DIM + col] = acc[i][j][t];
      }
}

extern "C" void kernel_launch(void* const* d_in, const int* in_sizes, int n_in,
                              void* d_out, int out_size, void* d_ws, size_t ws_size,
                              hipStream_t stream) {
  const float* H  = (const float*)d_in[0];   // (8192, 2048) fp32
  const float* W1 = (const float*)d_in[1];   // (8, 2048, 4096) fp32
  const float* W2 = (const float*)d_in[2];   // (8, 2048, 2048) fp32
  float* OUT = (float*)d_out;                // (8192, 2048) fp32
  uint16_t* ACT = (uint16_t*)d_ws;           // 8*1024*2048 bf16 = 33.5 MB

  dim3 blk(256);
  dim3 g1(DIM / BN, TOK / BM, NEXP);         // 16 x 8 x 8
  k_gateup<<<g1, blk, 0, stream>>>(H, W1, ACT);
  dim3 g2(DIM / BN, TOK / BM, NEXP);
  k_down<<<g2, blk, 0, stream>>>(ACT, W2, OUT);
}